// Round 1
// baseline (778.517 us; speedup 1.0000x reference)
//
#include <hip/hip_runtime.h>
#include <math.h>

#define LN_EPS 1e-5f

__device__ __forceinline__ float dot4(float4 a, float4 b) {
    return a.x*b.x + a.y*b.y + a.z*b.z + a.w*b.w;
}

// ---------------------------------------------------------------------------
// Kernel 1: time embedding + {q,k} projection + layer norm.
// Blocks 0..31   -> query rows (4 per block, NT=128), t = i/127
// Blocks 32..1055-> key rows   (4 per block, B*T=4096), t = timesteps[b*512+ti]
// q output is pre-scaled by 1/sqrt(128).
// ---------------------------------------------------------------------------
__global__ void k_embed_proj(
    const float* __restrict__ timesteps,
    const float* __restrict__ pw, const float* __restrict__ pb,
    const float* __restrict__ lw, const float* __restrict__ lb,
    const float* __restrict__ q_w, const float* __restrict__ q_b,
    const float* __restrict__ q_g, const float* __restrict__ q_be,
    const float* __restrict__ k_w, const float* __restrict__ k_b,
    const float* __restrict__ k_g, const float* __restrict__ k_be,
    float* __restrict__ qs, float* __restrict__ kmat)
{
    const int blk = blockIdx.x;
    const bool isq = blk < 32;
    const int j = threadIdx.x;            // 0..127

    __shared__ __align__(16) float e[4][128];
    __shared__ __align__(16) float4 red[128];

    float tv[4];
    int kidx0 = 0;
    if (isq) {
        const int q0 = blk * 4;
        #pragma unroll
        for (int r = 0; r < 4; ++r) tv[r] = (float)(q0 + r) * (1.0f/127.0f);
    } else {
        kidx0 = (blk - 32) * 4;
        #pragma unroll
        for (int r = 0; r < 4; ++r) tv[r] = timesteps[kidx0 + r];
    }

    float pwj = 0.f, pbj = 0.f;
    if (j > 0) { pwj = pw[j-1]; pbj = pb[j-1]; }
    const float lw0 = lw[0], lb0 = lb[0];
    #pragma unroll
    for (int r = 0; r < 4; ++r)
        e[r][j] = (j == 0) ? (tv[r]*lw0 + lb0) : sinf(tv[r]*pwj + pbj);
    __syncthreads();

    const float* W  = isq ? q_w  : k_w;
    const float* Bv = isq ? q_b  : k_b;
    const float* G  = isq ? q_g  : k_g;
    const float* Be = isq ? q_be : k_be;

    float acc[4];
    const float bj = Bv[j];
    #pragma unroll
    for (int r = 0; r < 4; ++r) acc[r] = bj;

    const float4* wr = (const float4*)(W + (size_t)j*128);
    const float4* e0 = (const float4*)(&e[0][0]);
    const float4* e1 = (const float4*)(&e[1][0]);
    const float4* e2 = (const float4*)(&e[2][0]);
    const float4* e3 = (const float4*)(&e[3][0]);
    #pragma unroll
    for (int d4 = 0; d4 < 32; ++d4) {
        const float4 w4 = wr[d4];
        acc[0] += dot4(w4, e0[d4]);
        acc[1] += dot4(w4, e1[d4]);
        acc[2] += dot4(w4, e2[d4]);
        acc[3] += dot4(w4, e3[d4]);
    }

    // LayerNorm over j (128) for all 4 rows simultaneously (float4 reduce).
    red[j] = make_float4(acc[0], acc[1], acc[2], acc[3]);
    __syncthreads();
    for (int s = 64; s > 0; s >>= 1) {
        if (j < s) {
            float4 m = red[j]; const float4 o = red[j+s];
            m.x += o.x; m.y += o.y; m.z += o.z; m.w += o.w;
            red[j] = m;
        }
        __syncthreads();
    }
    float4 mean = red[0];
    mean.x *= (1.0f/128.0f); mean.y *= (1.0f/128.0f);
    mean.z *= (1.0f/128.0f); mean.w *= (1.0f/128.0f);
    __syncthreads();
    const float d0 = acc[0]-mean.x, d1 = acc[1]-mean.y,
                d2 = acc[2]-mean.z, d3 = acc[3]-mean.w;
    red[j] = make_float4(d0*d0, d1*d1, d2*d2, d3*d3);
    __syncthreads();
    for (int s = 64; s > 0; s >>= 1) {
        if (j < s) {
            float4 m = red[j]; const float4 o = red[j+s];
            m.x += o.x; m.y += o.y; m.z += o.z; m.w += o.w;
            red[j] = m;
        }
        __syncthreads();
    }
    float4 var = red[0];
    var.x *= (1.0f/128.0f); var.y *= (1.0f/128.0f);
    var.z *= (1.0f/128.0f); var.w *= (1.0f/128.0f);

    const float gg = G[j], bb = Be[j];
    const float o0 = d0*rsqrtf(var.x+LN_EPS)*gg + bb;
    const float o1 = d1*rsqrtf(var.y+LN_EPS)*gg + bb;
    const float o2 = d2*rsqrtf(var.z+LN_EPS)*gg + bb;
    const float o3 = d3*rsqrtf(var.w+LN_EPS)*gg + bb;

    if (isq) {
        const float sc = 0.08838834764831845f;   // 1/sqrt(128)
        const int q0 = blk*4;
        qs[(size_t)(q0+0)*128 + j] = o0*sc;
        qs[(size_t)(q0+1)*128 + j] = o1*sc;
        qs[(size_t)(q0+2)*128 + j] = o2*sc;
        qs[(size_t)(q0+3)*128 + j] = o3*sc;
    } else {
        kmat[(size_t)(kidx0+0)*128 + j] = o0;
        kmat[(size_t)(kidx0+1)*128 + j] = o1;
        kmat[(size_t)(kidx0+2)*128 + j] = o2;
        kmat[(size_t)(kidx0+3)*128 + j] = o3;
    }
}

// ---------------------------------------------------------------------------
// Kernel 2: per (b, qi) block: scores -> per-channel masked softmax ->
// att -> LN(attn) -> out linear -> LN -> outm (B, NT, 128)
// ---------------------------------------------------------------------------
__global__ void k_attn(
    const float* __restrict__ input, const float* __restrict__ mask,
    const float* __restrict__ qs, const float* __restrict__ kmat,
    const float* __restrict__ attn_g, const float* __restrict__ attn_b,
    const float* __restrict__ out_w, const float* __restrict__ out_b,
    const float* __restrict__ out_g, const float* __restrict__ out_be,
    float* __restrict__ outm)
{
    const int bq = blockIdx.x;        // b*128 + qi
    const int b  = bq >> 7;
    const int qi = bq & 127;
    const int tid = threadIdx.x;      // 0..127

    __shared__ __align__(16) float sc[512];
    __shared__ __align__(16) float ql[128];
    __shared__ __align__(16) float redA[128];
    __shared__ __align__(16) float redB[128];
    __shared__ __align__(16) float x2[64];

    ql[tid] = qs[(size_t)qi*128 + tid];
    __syncthreads();

    const float4* q4 = (const float4*)ql;
    #pragma unroll
    for (int it = 0; it < 4; ++it) {
        const int t = tid + it*128;
        const float4* kr = (const float4*)(kmat + (size_t)(b*512 + t)*128);
        float a0=0.f, a1=0.f, a2=0.f, a3=0.f;
        #pragma unroll
        for (int d4 = 0; d4 < 32; d4 += 4) {
            a0 += dot4(q4[d4+0], kr[d4+0]);
            a1 += dot4(q4[d4+1], kr[d4+1]);
            a2 += dot4(q4[d4+2], kr[d4+2]);
            a3 += dot4(q4[d4+3], kr[d4+3]);
        }
        sc[t] = (a0+a1)+(a2+a3);
    }
    __syncthreads();

    // per-channel masked softmax over keys; channel c = tid&63, half of T each
    const int c    = tid & 63;
    const int half = tid >> 6;
    const int t0   = half * 256;
    const float* mrow = mask  + (size_t)(b*32 + (c & 31))*512;
    const float* xrow = input + (size_t)(b*32 + (c & 31))*512;
    const bool isin = (c < 32);

    float M = -1e30f;
    for (int t = t0; t < t0+256; ++t)
        if (mrow[t] == 0.0f) M = fmaxf(M, sc[t]);
    redA[tid] = M;
    __syncthreads();
    const float Mc = fmaxf(redA[c], redA[c+64]);
    __syncthreads();

    float s = 0.f, a = 0.f;
    if (Mc > -1e29f) {
        for (int t = t0; t < t0+256; ++t) {
            if (mrow[t] == 0.0f) {
                const float ee = expf(sc[t] - Mc);
                s += ee;
                a += ee * (isin ? xrow[t] : 1.0f);
            }
        }
    }
    redA[tid] = s; redB[tid] = a;
    __syncthreads();

    float attv = 0.f;
    if (tid < 64) {
        const float st = redA[tid] + redA[tid+64];
        const float at = redB[tid] + redB[tid+64];
        attv = (st > 0.f) ? at/st : 0.f;
    }
    __syncthreads();

    // LayerNorm over 64 channels
    redA[tid] = (tid < 64) ? attv : 0.f;
    __syncthreads();
    for (int s2 = 64; s2 > 0; s2 >>= 1) {
        if (tid < s2) redA[tid] += redA[tid+s2];
        __syncthreads();
    }
    const float mean64 = redA[0] * (1.0f/64.0f);
    __syncthreads();
    const float dv = attv - mean64;
    redA[tid] = (tid < 64) ? dv*dv : 0.f;
    __syncthreads();
    for (int s2 = 64; s2 > 0; s2 >>= 1) {
        if (tid < s2) redA[tid] += redA[tid+s2];
        __syncthreads();
    }
    const float var64 = redA[0] * (1.0f/64.0f);
    __syncthreads();
    if (tid < 64) x2[tid] = dv*rsqrtf(var64+LN_EPS)*attn_g[tid] + attn_b[tid];
    __syncthreads();

    // out linear (128 x 64) + LayerNorm over 128
    float acc = out_b[tid];
    const float4* wr  = (const float4*)(out_w + (size_t)tid*64);
    const float4* x24 = (const float4*)x2;
    #pragma unroll
    for (int d4 = 0; d4 < 16; ++d4) acc += dot4(wr[d4], x24[d4]);

    redA[tid] = acc;
    __syncthreads();
    for (int s2 = 64; s2 > 0; s2 >>= 1) {
        if (tid < s2) redA[tid] += redA[tid+s2];
        __syncthreads();
    }
    const float mean128 = redA[0] * (1.0f/128.0f);
    __syncthreads();
    const float d = acc - mean128;
    redA[tid] = d*d;
    __syncthreads();
    for (int s2 = 64; s2 > 0; s2 >>= 1) {
        if (tid < s2) redA[tid] += redA[tid+s2];
        __syncthreads();
    }
    const float var128 = redA[0] * (1.0f/128.0f);

    outm[(size_t)(b*128+qi)*128 + tid] =
        d*rsqrtf(var128+LN_EPS)*out_g[tid] + out_be[tid];
}

// ---------------------------------------------------------------------------
// Kernel 3: gi[qi][b][g] = outm[b,qi,:]·wih[g,:] + bih[g]  (parallel over qi)
// 128 blocks (one per qi), 384 threads, 8 batch rows amortize weight loads.
// ---------------------------------------------------------------------------
__global__ void k_gi(const float* __restrict__ outm,
                     const float* __restrict__ wih, const float* __restrict__ bih,
                     float* __restrict__ gi)
{
    const int qi  = blockIdx.x;
    const int tid = threadIdx.x;   // 0..383
    __shared__ __align__(16) float rows[8][128];
    for (int idx = tid; idx < 1024; idx += 384) {
        const int b = idx >> 7, d = idx & 127;
        rows[b][d] = outm[(size_t)(b*128+qi)*128 + d];
    }
    __syncthreads();

    const float4* wr = (const float4*)(wih + (size_t)tid*128);
    float acc[8] = {0,0,0,0,0,0,0,0};
    #pragma unroll 8
    for (int d4 = 0; d4 < 32; ++d4) {
        const float4 w4 = wr[d4];
        #pragma unroll
        for (int b = 0; b < 8; ++b)
            acc[b] += dot4(w4, ((const float4*)rows[b])[d4]);
    }
    const float bi = bih[tid];
    #pragma unroll
    for (int b = 0; b < 8; ++b)
        gi[((size_t)qi*8 + b)*384 + tid] = acc[b] + bi;
}

// ---------------------------------------------------------------------------
// Kernel 4: GRU recurrence, one block per batch row (independent!).
// 384 threads = one per gate element; h double-buffered in LDS.
// ---------------------------------------------------------------------------
__global__ void k_gru(const float* __restrict__ gi,
                      const float* __restrict__ whh, const float* __restrict__ bhh,
                      float* __restrict__ hout)
{
    const int b = blockIdx.x;
    const int g = threadIdx.x;     // 0..383
    __shared__ __align__(16) float h[2][128];
    __shared__ __align__(16) float gh[384];
    __shared__ __align__(16) float gia[384];

    if (g < 128) h[0][g] = 0.f;
    __syncthreads();

    const float4* wr = (const float4*)(whh + (size_t)g*128);
    const float bh = bhh[g];
    int p = 0;
    for (int qi = 0; qi < 128; ++qi) {
        gia[g] = gi[((size_t)qi*8 + b)*384 + g];
        const float4* h4 = (const float4*)h[p];
        float a0=0.f, a1=0.f, a2=0.f, a3=0.f;
        #pragma unroll
        for (int d4 = 0; d4 < 32; d4 += 4) {
            a0 += dot4(wr[d4+0], h4[d4+0]);
            a1 += dot4(wr[d4+1], h4[d4+1]);
            a2 += dot4(wr[d4+2], h4[d4+2]);
            a3 += dot4(wr[d4+3], h4[d4+3]);
        }
        gh[g] = bh + ((a0+a1)+(a2+a3));
        __syncthreads();
        if (g < 128) {
            const float r = 1.f/(1.f + expf(-(gia[g]     + gh[g])));
            const float z = 1.f/(1.f + expf(-(gia[g+128] + gh[g+128])));
            const float n = tanhf(gia[g+256] + r*gh[g+256]);
            h[1-p][g] = (1.f - z)*n + z*h[p][g];
        }
        __syncthreads();
        p ^= 1;
    }
    if (g < 128) hout[(size_t)b*128 + g] = h[p][g];
}

// ---------------------------------------------------------------------------
// Kernel 5: classifier MLP head -> logits (8, 2)
// ---------------------------------------------------------------------------
__global__ void k_cls(const float* __restrict__ hlast,
                      const float* __restrict__ c1w, const float* __restrict__ c1b,
                      const float* __restrict__ c2w, const float* __restrict__ c2b,
                      const float* __restrict__ c3w, const float* __restrict__ c3b,
                      float* __restrict__ out)
{
    const int b = blockIdx.x;
    const int j = threadIdx.x;   // 0..127
    __shared__ __align__(16) float v0[128];
    __shared__ __align__(16) float v1[128];

    v0[j] = hlast[(size_t)b*128 + j];
    __syncthreads();

    float acc = c1b[j];
    {
        const float4* w = (const float4*)(c1w + (size_t)j*128);
        const float4* v = (const float4*)v0;
        #pragma unroll
        for (int d4 = 0; d4 < 32; ++d4) acc += dot4(w[d4], v[d4]);
    }
    v1[j] = fmaxf(acc, 0.f);
    __syncthreads();

    acc = c2b[j];
    {
        const float4* w = (const float4*)(c2w + (size_t)j*128);
        const float4* v = (const float4*)v1;
        #pragma unroll
        for (int d4 = 0; d4 < 32; ++d4) acc += dot4(w[d4], v[d4]);
    }
    v0[j] = fmaxf(acc, 0.f);
    __syncthreads();

    if (j < 2) {
        acc = c3b[j];
        const float4* w = (const float4*)(c3w + (size_t)j*128);
        const float4* v = (const float4*)v0;
        #pragma unroll
        for (int d4 = 0; d4 < 32; ++d4) acc += dot4(w[d4], v[d4]);
        out[(size_t)b*2 + j] = acc;
    }
}

// ---------------------------------------------------------------------------
extern "C" void kernel_launch(void* const* d_in, const int* in_sizes, int n_in,
                              void* d_out, int out_size, void* d_ws, size_t ws_size,
                              hipStream_t stream)
{
    const float* input     = (const float*)d_in[0];
    const float* mask      = (const float*)d_in[1];
    const float* timesteps = (const float*)d_in[2];
    const float* pw        = (const float*)d_in[3];
    const float* pb        = (const float*)d_in[4];
    const float* lw        = (const float*)d_in[5];
    const float* lb        = (const float*)d_in[6];
    const float* q_w       = (const float*)d_in[7];
    const float* q_b       = (const float*)d_in[8];
    const float* q_g       = (const float*)d_in[9];
    const float* q_be      = (const float*)d_in[10];
    const float* k_w       = (const float*)d_in[11];
    const float* k_b       = (const float*)d_in[12];
    const float* k_g       = (const float*)d_in[13];
    const float* k_be      = (const float*)d_in[14];
    const float* attn_g    = (const float*)d_in[15];
    const float* attn_b    = (const float*)d_in[16];
    const float* out_w     = (const float*)d_in[17];
    const float* out_b     = (const float*)d_in[18];
    const float* out_g     = (const float*)d_in[19];
    const float* out_be    = (const float*)d_in[20];
    const float* gru_wih   = (const float*)d_in[21];
    const float* gru_whh   = (const float*)d_in[22];
    const float* gru_bih   = (const float*)d_in[23];
    const float* gru_bhh   = (const float*)d_in[24];
    const float* c1_w      = (const float*)d_in[25];
    const float* c1_b      = (const float*)d_in[26];
    const float* c2_w      = (const float*)d_in[27];
    const float* c2_b      = (const float*)d_in[28];
    const float* c3_w      = (const float*)d_in[29];
    const float* c3_b      = (const float*)d_in[30];

    float* ws   = (float*)d_ws;
    float* qs   = ws;                    // 128*128        = 16384
    float* kmat = qs   + 16384;          // 8*512*128      = 524288
    float* outm = kmat + 524288;         // 8*128*128      = 131072
    float* gi   = outm + 131072;         // 128*8*384      = 393216
    float* hl   = gi   + 393216;         // 8*128          = 1024

    k_embed_proj<<<1056, 128, 0, stream>>>(timesteps, pw, pb, lw, lb,
                                           q_w, q_b, q_g, q_be,
                                           k_w, k_b, k_g, k_be, qs, kmat);
    k_attn<<<1024, 128, 0, stream>>>(input, mask, qs, kmat,
                                     attn_g, attn_b, out_w, out_b,
                                     out_g, out_be, outm);
    k_gi<<<128, 384, 0, stream>>>(outm, gru_wih, gru_bih, gi);
    k_gru<<<8, 384, 0, stream>>>(gi, gru_whh, gru_bhh, hl);
    k_cls<<<8, 128, 0, stream>>>(hl, c1_w, c1_b, c2_w, c2_b, c3_w, c3_b,
                                 (float*)d_out);
}

// Round 2
// 430.530 us; speedup vs baseline: 1.8083x; 1.8083x over previous
//
#include <hip/hip_runtime.h>
#include <math.h>

#define LN_EPS 1e-5f

__device__ __forceinline__ float dot4(float4 a, float4 b) {
    return a.x*b.x + a.y*b.y + a.z*b.z + a.w*b.w;
}
__device__ __forceinline__ float fast_sigmoid(float x) {
    return 1.f / (1.f + __expf(-x));          // x=+-inf safe
}
__device__ __forceinline__ float fast_tanh(float x) {
    const float e = __expf(2.f * x);          // inf-safe form
    return 1.f - 2.f / (e + 1.f);
}

// ---------------------------------------------------------------------------
// Kernel 1: time embedding + {q,k} projection + layer norm.
// Blocks 0..31   -> query rows (4 per block, NT=128), t = i/127
// Blocks 32..1055-> key rows   (4 per block, B*T=4096), t = timesteps[b*512+ti]
// q output is pre-scaled by 1/sqrt(128).
// ---------------------------------------------------------------------------
__global__ void k_embed_proj(
    const float* __restrict__ timesteps,
    const float* __restrict__ pw, const float* __restrict__ pb,
    const float* __restrict__ lw, const float* __restrict__ lb,
    const float* __restrict__ q_w, const float* __restrict__ q_b,
    const float* __restrict__ q_g, const float* __restrict__ q_be,
    const float* __restrict__ k_w, const float* __restrict__ k_b,
    const float* __restrict__ k_g, const float* __restrict__ k_be,
    float* __restrict__ qs, float* __restrict__ kmat)
{
    const int blk = blockIdx.x;
    const bool isq = blk < 32;
    const int j = threadIdx.x;            // 0..127

    __shared__ __align__(16) float e[4][128];
    __shared__ __align__(16) float4 red[128];

    float tv[4];
    int kidx0 = 0;
    if (isq) {
        const int q0 = blk * 4;
        #pragma unroll
        for (int r = 0; r < 4; ++r) tv[r] = (float)(q0 + r) * (1.0f/127.0f);
    } else {
        kidx0 = (blk - 32) * 4;
        #pragma unroll
        for (int r = 0; r < 4; ++r) tv[r] = timesteps[kidx0 + r];
    }

    float pwj = 0.f, pbj = 0.f;
    if (j > 0) { pwj = pw[j-1]; pbj = pb[j-1]; }
    const float lw0 = lw[0], lb0 = lb[0];
    #pragma unroll
    for (int r = 0; r < 4; ++r)
        e[r][j] = (j == 0) ? (tv[r]*lw0 + lb0) : sinf(tv[r]*pwj + pbj);
    __syncthreads();

    const float* W  = isq ? q_w  : k_w;
    const float* Bv = isq ? q_b  : k_b;
    const float* G  = isq ? q_g  : k_g;
    const float* Be = isq ? q_be : k_be;

    float acc[4];
    const float bj = Bv[j];
    #pragma unroll
    for (int r = 0; r < 4; ++r) acc[r] = bj;

    const float4* wr = (const float4*)(W + (size_t)j*128);
    const float4* e0 = (const float4*)(&e[0][0]);
    const float4* e1 = (const float4*)(&e[1][0]);
    const float4* e2 = (const float4*)(&e[2][0]);
    const float4* e3 = (const float4*)(&e[3][0]);
    #pragma unroll
    for (int d4 = 0; d4 < 32; ++d4) {
        const float4 w4 = wr[d4];
        acc[0] += dot4(w4, e0[d4]);
        acc[1] += dot4(w4, e1[d4]);
        acc[2] += dot4(w4, e2[d4]);
        acc[3] += dot4(w4, e3[d4]);
    }

    red[j] = make_float4(acc[0], acc[1], acc[2], acc[3]);
    __syncthreads();
    for (int s = 64; s > 0; s >>= 1) {
        if (j < s) {
            float4 m = red[j]; const float4 o = red[j+s];
            m.x += o.x; m.y += o.y; m.z += o.z; m.w += o.w;
            red[j] = m;
        }
        __syncthreads();
    }
    float4 mean = red[0];
    mean.x *= (1.0f/128.0f); mean.y *= (1.0f/128.0f);
    mean.z *= (1.0f/128.0f); mean.w *= (1.0f/128.0f);
    __syncthreads();
    const float d0 = acc[0]-mean.x, d1 = acc[1]-mean.y,
                d2 = acc[2]-mean.z, d3 = acc[3]-mean.w;
    red[j] = make_float4(d0*d0, d1*d1, d2*d2, d3*d3);
    __syncthreads();
    for (int s = 64; s > 0; s >>= 1) {
        if (j < s) {
            float4 m = red[j]; const float4 o = red[j+s];
            m.x += o.x; m.y += o.y; m.z += o.z; m.w += o.w;
            red[j] = m;
        }
        __syncthreads();
    }
    float4 var = red[0];
    var.x *= (1.0f/128.0f); var.y *= (1.0f/128.0f);
    var.z *= (1.0f/128.0f); var.w *= (1.0f/128.0f);

    const float gg = G[j], bb = Be[j];
    const float o0 = d0*rsqrtf(var.x+LN_EPS)*gg + bb;
    const float o1 = d1*rsqrtf(var.y+LN_EPS)*gg + bb;
    const float o2 = d2*rsqrtf(var.z+LN_EPS)*gg + bb;
    const float o3 = d3*rsqrtf(var.w+LN_EPS)*gg + bb;

    if (isq) {
        const float sc = 0.08838834764831845f;   // 1/sqrt(128)
        const int q0 = blk*4;
        qs[(size_t)(q0+0)*128 + j] = o0*sc;
        qs[(size_t)(q0+1)*128 + j] = o1*sc;
        qs[(size_t)(q0+2)*128 + j] = o2*sc;
        qs[(size_t)(q0+3)*128 + j] = o3*sc;
    } else {
        kmat[(size_t)(kidx0+0)*128 + j] = o0;
        kmat[(size_t)(kidx0+1)*128 + j] = o1;
        kmat[(size_t)(kidx0+2)*128 + j] = o2;
        kmat[(size_t)(kidx0+3)*128 + j] = o3;
    }
}

// ---------------------------------------------------------------------------
// Kernel 2: per (b, qi) block.
// Structure exploited:
//  - e^{score_t} is channel-independent -> computed once into et[512].
//  - channels 32..63 (mask half): x == unmask indicator => att = 1 (or 0 if
//    the channel is fully masked, matching reference's x==0-everywhere case).
//  - no max subtraction needed: |score| small, fp32 exp is safe.
// Then attn-LN(64) -> out linear (128x64) -> LN(128) -> outm.
// ---------------------------------------------------------------------------
__global__ void k_attn(
    const float* __restrict__ input, const float* __restrict__ mask,
    const float* __restrict__ qs, const float* __restrict__ kmat,
    const float* __restrict__ attn_g, const float* __restrict__ attn_b,
    const float* __restrict__ out_w, const float* __restrict__ out_b,
    const float* __restrict__ out_g, const float* __restrict__ out_be,
    float* __restrict__ outm)
{
    const int bq = blockIdx.x;        // b*128 + qi
    const int b  = bq >> 7;
    const int qi = bq & 127;
    const int tid = threadIdx.x;      // 0..127

    __shared__ __align__(16) float et[512];
    __shared__ __align__(16) float ql[128];
    __shared__ __align__(16) float redA[128];
    __shared__ __align__(16) float redB[128];
    __shared__ __align__(16) float x2[64];

    ql[tid] = qs[(size_t)qi*128 + tid];
    __syncthreads();

    const float4* q4 = (const float4*)ql;
    #pragma unroll
    for (int it = 0; it < 4; ++it) {
        const int t = tid + it*128;
        const float4* kr = (const float4*)(kmat + (size_t)(b*512 + t)*128);
        float a0=0.f, a1=0.f, a2=0.f, a3=0.f;
        #pragma unroll
        for (int d4 = 0; d4 < 32; d4 += 4) {
            a0 += dot4(q4[d4+0], kr[d4+0]);
            a1 += dot4(q4[d4+1], kr[d4+1]);
            a2 += dot4(q4[d4+2], kr[d4+2]);
            a3 += dot4(q4[d4+3], kr[d4+3]);
        }
        et[t] = __expf((a0+a1)+(a2+a3));
    }
    __syncthreads();

    // scan only the 32 input channels; 4 threads per channel, 128 keys each
    const int c   = tid & 31;
    const int seg = tid >> 5;
    const float4* m4 = (const float4*)(mask  + (size_t)(b*32 + c)*512) + seg*32;
    const float4* x4 = (const float4*)(input + (size_t)(b*32 + c)*512) + seg*32;
    const float4* e4 = (const float4*)et + seg*32;

    float s = 0.f, a = 0.f;
    #pragma unroll 8
    for (int i = 0; i < 32; ++i) {
        const float4 mm = m4[i];
        const float4 xx = x4[i];
        const float4 ee = e4[i];
        if (mm.x == 0.f) { s += ee.x; a += ee.x*xx.x; }
        if (mm.y == 0.f) { s += ee.y; a += ee.y*xx.y; }
        if (mm.z == 0.f) { s += ee.z; a += ee.z*xx.z; }
        if (mm.w == 0.f) { s += ee.w; a += ee.w*xx.w; }
    }
    redA[tid] = s; redB[tid] = a;
    __syncthreads();

    float attv = 0.f;
    if (tid < 64) {
        if (tid < 32) {
            const float ss = redA[tid]+redA[tid+32]+redA[tid+64]+redA[tid+96];
            const float aa = redB[tid]+redB[tid+32]+redB[tid+64]+redB[tid+96];
            attv = (ss > 0.f) ? aa/ss : 0.f;
        } else {
            // x == unmask indicator: softmax-weighted average is exactly 1
            // unless the channel is fully masked (then x==0 everywhere -> 0).
            const int cc = tid - 32;
            const float ss = redA[cc]+redA[cc+32]+redA[cc+64]+redA[cc+96];
            attv = (ss > 0.f) ? 1.0f : 0.0f;
        }
    }
    __syncthreads();

    // LayerNorm over 64 channels
    redA[tid] = (tid < 64) ? attv : 0.f;
    __syncthreads();
    for (int s2 = 64; s2 > 0; s2 >>= 1) {
        if (tid < s2) redA[tid] += redA[tid+s2];
        __syncthreads();
    }
    const float mean64 = redA[0] * (1.0f/64.0f);
    __syncthreads();
    const float dv = attv - mean64;
    redA[tid] = (tid < 64) ? dv*dv : 0.f;
    __syncthreads();
    for (int s2 = 64; s2 > 0; s2 >>= 1) {
        if (tid < s2) redA[tid] += redA[tid+s2];
        __syncthreads();
    }
    const float var64 = redA[0] * (1.0f/64.0f);
    __syncthreads();
    if (tid < 64) x2[tid] = dv*rsqrtf(var64+LN_EPS)*attn_g[tid] + attn_b[tid];
    __syncthreads();

    // out linear (128 x 64) + LayerNorm over 128
    float acc = out_b[tid];
    const float4* wr  = (const float4*)(out_w + (size_t)tid*64);
    const float4* x24 = (const float4*)x2;
    #pragma unroll
    for (int d4 = 0; d4 < 16; ++d4) acc += dot4(wr[d4], x24[d4]);

    redA[tid] = acc;
    __syncthreads();
    for (int s2 = 64; s2 > 0; s2 >>= 1) {
        if (tid < s2) redA[tid] += redA[tid+s2];
        __syncthreads();
    }
    const float mean128 = redA[0] * (1.0f/128.0f);
    __syncthreads();
    const float d = acc - mean128;
    redA[tid] = d*d;
    __syncthreads();
    for (int s2 = 64; s2 > 0; s2 >>= 1) {
        if (tid < s2) redA[tid] += redA[tid+s2];
        __syncthreads();
    }
    const float var128 = redA[0] * (1.0f/128.0f);

    outm[(size_t)(b*128+qi)*128 + tid] =
        d*rsqrtf(var128+LN_EPS)*out_g[tid] + out_be[tid];
}

// ---------------------------------------------------------------------------
// Kernel 3: gi[qi][b][g] = outm[b,qi,:]·wih[g,:] + bih[g]  (parallel over qi)
// ---------------------------------------------------------------------------
__global__ void k_gi(const float* __restrict__ outm,
                     const float* __restrict__ wih, const float* __restrict__ bih,
                     float* __restrict__ gi)
{
    const int qi  = blockIdx.x;
    const int tid = threadIdx.x;   // 0..383
    __shared__ __align__(16) float rows[8][128];
    for (int idx = tid; idx < 1024; idx += 384) {
        const int b = idx >> 7, d = idx & 127;
        rows[b][d] = outm[(size_t)(b*128+qi)*128 + d];
    }
    __syncthreads();

    const float4* wr = (const float4*)(wih + (size_t)tid*128);
    float acc[8] = {0,0,0,0,0,0,0,0};
    #pragma unroll 8
    for (int d4 = 0; d4 < 32; ++d4) {
        const float4 w4 = wr[d4];
        #pragma unroll
        for (int b = 0; b < 8; ++b)
            acc[b] += dot4(w4, ((const float4*)rows[b])[d4]);
    }
    const float bi = bih[tid];
    #pragma unroll
    for (int b = 0; b < 8; ++b)
        gi[((size_t)qi*8 + b)*384 + tid] = acc[b] + bi;
}

// ---------------------------------------------------------------------------
// Kernel 4: GRU recurrence, one block per batch row.
// whh row held in 128 VGPRs per thread (loaded ONCE); gia triple prefetched
// one step ahead so global latency is off the critical path. Per step:
// LDS-broadcast h reads + register FMAs + 2 barriers.
// ---------------------------------------------------------------------------
__global__ void __launch_bounds__(384, 2) k_gru(
    const float* __restrict__ gi,
    const float* __restrict__ whh, const float* __restrict__ bhh,
    float* __restrict__ hout)
{
    const int b = blockIdx.x;
    const int g = threadIdx.x;     // 0..383
    __shared__ __align__(16) float h[2][128];
    __shared__ __align__(16) float gh[384];

    // weight row -> registers (once)
    float4 w[32];
    {
        const float4* wr = (const float4*)(whh + (size_t)g*128);
        #pragma unroll
        for (int i = 0; i < 32; ++i) w[i] = wr[i];
    }
    const float bh = bhh[g];

    if (g < 128) h[0][g] = 0.f;

    // prefetch step-0 gia triple (only gate threads need it)
    const float* gbase = gi + (size_t)b*384;     // + qi*3072 per step
    float gr0 = 0.f, gz0 = 0.f, gn0 = 0.f;
    if (g < 128) {
        gr0 = gbase[g];
        gz0 = gbase[g+128];
        gn0 = gbase[g+256];
    }
    __syncthreads();

    int p = 0;
    for (int qi = 0; qi < 128; ++qi) {
        const float4* h4 = (const float4*)h[p];
        float a0=0.f, a1=0.f, a2=0.f, a3=0.f;
        #pragma unroll
        for (int d4 = 0; d4 < 32; d4 += 4) {
            a0 += dot4(w[d4+0], h4[d4+0]);
            a1 += dot4(w[d4+1], h4[d4+1]);
            a2 += dot4(w[d4+2], h4[d4+2]);
            a3 += dot4(w[d4+3], h4[d4+3]);
        }
        gh[g] = bh + ((a0+a1)+(a2+a3));

        // prefetch next step's gia while the dot result drains
        float grn = 0.f, gzn = 0.f, gnn = 0.f;
        if (g < 128 && qi < 127) {
            const float* gb = gbase + (size_t)(qi+1)*3072;
            grn = gb[g]; gzn = gb[g+128]; gnn = gb[g+256];
        }
        __syncthreads();

        if (g < 128) {
            const float r = fast_sigmoid(gr0 + gh[g]);
            const float z = fast_sigmoid(gz0 + gh[g+128]);
            const float n = fast_tanh(gn0 + r*gh[g+256]);
            h[1-p][g] = (1.f - z)*n + z*h[p][g];
            gr0 = grn; gz0 = gzn; gn0 = gnn;
        }
        __syncthreads();
        p ^= 1;
    }
    if (g < 128) hout[(size_t)b*128 + g] = h[p][g];
}

// ---------------------------------------------------------------------------
// Kernel 5: classifier MLP head -> logits (8, 2)
// ---------------------------------------------------------------------------
__global__ void k_cls(const float* __restrict__ hlast,
                      const float* __restrict__ c1w, const float* __restrict__ c1b,
                      const float* __restrict__ c2w, const float* __restrict__ c2b,
                      const float* __restrict__ c3w, const float* __restrict__ c3b,
                      float* __restrict__ out)
{
    const int b = blockIdx.x;
    const int j = threadIdx.x;   // 0..127
    __shared__ __align__(16) float v0[128];
    __shared__ __align__(16) float v1[128];

    v0[j] = hlast[(size_t)b*128 + j];
    __syncthreads();

    float acc = c1b[j];
    {
        const float4* w = (const float4*)(c1w + (size_t)j*128);
        const float4* v = (const float4*)v0;
        #pragma unroll
        for (int d4 = 0; d4 < 32; ++d4) acc += dot4(w[d4], v[d4]);
    }
    v1[j] = fmaxf(acc, 0.f);
    __syncthreads();

    acc = c2b[j];
    {
        const float4* w = (const float4*)(c2w + (size_t)j*128);
        const float4* v = (const float4*)v1;
        #pragma unroll
        for (int d4 = 0; d4 < 32; ++d4) acc += dot4(w[d4], v[d4]);
    }
    v0[j] = fmaxf(acc, 0.f);
    __syncthreads();

    if (j < 2) {
        acc = c3b[j];
        const float4* w = (const float4*)(c3w + (size_t)j*128);
        const float4* v = (const float4*)v0;
        #pragma unroll
        for (int d4 = 0; d4 < 32; ++d4) acc += dot4(w[d4], v[d4]);
        out[(size_t)b*2 + j] = acc;
    }
}

// ---------------------------------------------------------------------------
extern "C" void kernel_launch(void* const* d_in, const int* in_sizes, int n_in,
                              void* d_out, int out_size, void* d_ws, size_t ws_size,
                              hipStream_t stream)
{
    const float* input     = (const float*)d_in[0];
    const float* mask      = (const float*)d_in[1];
    const float* timesteps = (const float*)d_in[2];
    const float* pw        = (const float*)d_in[3];
    const float* pb        = (const float*)d_in[4];
    const float* lw        = (const float*)d_in[5];
    const float* lb        = (const float*)d_in[6];
    const float* q_w       = (const float*)d_in[7];
    const float* q_b       = (const float*)d_in[8];
    const float* q_g       = (const float*)d_in[9];
    const float* q_be      = (const float*)d_in[10];
    const float* k_w       = (const float*)d_in[11];
    const float* k_b       = (const float*)d_in[12];
    const float* k_g       = (const float*)d_in[13];
    const float* k_be      = (const float*)d_in[14];
    const float* attn_g    = (const float*)d_in[15];
    const float* attn_b    = (const float*)d_in[16];
    const float* out_w     = (const float*)d_in[17];
    const float* out_b     = (const float*)d_in[18];
    const float* out_g     = (const float*)d_in[19];
    const float* out_be    = (const float*)d_in[20];
    const float* gru_wih   = (const float*)d_in[21];
    const float* gru_whh   = (const float*)d_in[22];
    const float* gru_bih   = (const float*)d_in[23];
    const float* gru_bhh   = (const float*)d_in[24];
    const float* c1_w      = (const float*)d_in[25];
    const float* c1_b      = (const float*)d_in[26];
    const float* c2_w      = (const float*)d_in[27];
    const float* c2_b      = (const float*)d_in[28];
    const float* c3_w      = (const float*)d_in[29];
    const float* c3_b      = (const float*)d_in[30];

    float* ws   = (float*)d_ws;
    float* qs   = ws;                    // 128*128        = 16384
    float* kmat = qs   + 16384;          // 8*512*128      = 524288
    float* outm = kmat + 524288;         // 8*128*128      = 131072
    float* gi   = outm + 131072;         // 128*8*384      = 393216
    float* hl   = gi   + 393216;         // 8*128          = 1024

    k_embed_proj<<<1056, 128, 0, stream>>>(timesteps, pw, pb, lw, lb,
                                           q_w, q_b, q_g, q_be,
                                           k_w, k_b, k_g, k_be, qs, kmat);
    k_attn<<<1024, 128, 0, stream>>>(input, mask, qs, kmat,
                                     attn_g, attn_b, out_w, out_b,
                                     out_g, out_be, outm);
    k_gi<<<128, 384, 0, stream>>>(outm, gru_wih, gru_bih, gi);
    k_gru<<<8, 384, 0, stream>>>(gi, gru_whh, gru_bhh, hl);
    k_cls<<<8, 128, 0, stream>>>(hl, c1_w, c1_b, c2_w, c2_b, c3_w, c3_b,
                                 (float*)d_out);
}

// Round 3
// 346.441 us; speedup vs baseline: 2.2472x; 1.2427x over previous
//
#include <hip/hip_runtime.h>
#include <math.h>

#define LN_EPS 1e-5f

__device__ __forceinline__ float dot4(float4 a, float4 b) {
    return a.x*b.x + a.y*b.y + a.z*b.z + a.w*b.w;
}
__device__ __forceinline__ float fast_sigmoid(float x) {
    return 1.f / (1.f + __expf(-x));
}
__device__ __forceinline__ float fast_tanh(float x) {
    const float e = __expf(2.f * x);
    return 1.f - 2.f / (e + 1.f);
}

// ---------------------------------------------------------------------------
// Kernel 1: time embedding + {q,k} projection + layer norm.
// Blocks 0..31   -> query rows (4/block, NT=128); 32..1055 -> key rows.
// q pre-scaled by 1/sqrt(128).
// ---------------------------------------------------------------------------
__global__ void k_embed_proj(
    const float* __restrict__ timesteps,
    const float* __restrict__ pw, const float* __restrict__ pb,
    const float* __restrict__ lw, const float* __restrict__ lb,
    const float* __restrict__ q_w, const float* __restrict__ q_b,
    const float* __restrict__ q_g, const float* __restrict__ q_be,
    const float* __restrict__ k_w, const float* __restrict__ k_b,
    const float* __restrict__ k_g, const float* __restrict__ k_be,
    float* __restrict__ qs, float* __restrict__ kmat)
{
    const int blk = blockIdx.x;
    const bool isq = blk < 32;
    const int j = threadIdx.x;            // 0..127

    __shared__ __align__(16) float e[4][128];
    __shared__ __align__(16) float4 red[128];

    float tv[4];
    int kidx0 = 0;
    if (isq) {
        const int q0 = blk * 4;
        #pragma unroll
        for (int r = 0; r < 4; ++r) tv[r] = (float)(q0 + r) * (1.0f/127.0f);
    } else {
        kidx0 = (blk - 32) * 4;
        #pragma unroll
        for (int r = 0; r < 4; ++r) tv[r] = timesteps[kidx0 + r];
    }

    float pwj = 0.f, pbj = 0.f;
    if (j > 0) { pwj = pw[j-1]; pbj = pb[j-1]; }
    const float lw0 = lw[0], lb0 = lb[0];
    #pragma unroll
    for (int r = 0; r < 4; ++r)
        e[r][j] = (j == 0) ? (tv[r]*lw0 + lb0) : sinf(tv[r]*pwj + pbj);
    __syncthreads();

    const float* W  = isq ? q_w  : k_w;
    const float* Bv = isq ? q_b  : k_b;
    const float* G  = isq ? q_g  : k_g;
    const float* Be = isq ? q_be : k_be;

    float acc[4];
    const float bj = Bv[j];
    #pragma unroll
    for (int r = 0; r < 4; ++r) acc[r] = bj;

    const float4* wr = (const float4*)(W + (size_t)j*128);
    const float4* e0 = (const float4*)(&e[0][0]);
    const float4* e1 = (const float4*)(&e[1][0]);
    const float4* e2 = (const float4*)(&e[2][0]);
    const float4* e3 = (const float4*)(&e[3][0]);
    #pragma unroll
    for (int d4 = 0; d4 < 32; ++d4) {
        const float4 w4 = wr[d4];
        acc[0] += dot4(w4, e0[d4]);
        acc[1] += dot4(w4, e1[d4]);
        acc[2] += dot4(w4, e2[d4]);
        acc[3] += dot4(w4, e3[d4]);
    }

    red[j] = make_float4(acc[0], acc[1], acc[2], acc[3]);
    __syncthreads();
    for (int s = 64; s > 0; s >>= 1) {
        if (j < s) {
            float4 m = red[j]; const float4 o = red[j+s];
            m.x += o.x; m.y += o.y; m.z += o.z; m.w += o.w;
            red[j] = m;
        }
        __syncthreads();
    }
    float4 mean = red[0];
    mean.x *= (1.0f/128.0f); mean.y *= (1.0f/128.0f);
    mean.z *= (1.0f/128.0f); mean.w *= (1.0f/128.0f);
    __syncthreads();
    const float d0 = acc[0]-mean.x, d1 = acc[1]-mean.y,
                d2 = acc[2]-mean.z, d3 = acc[3]-mean.w;
    red[j] = make_float4(d0*d0, d1*d1, d2*d2, d3*d3);
    __syncthreads();
    for (int s = 64; s > 0; s >>= 1) {
        if (j < s) {
            float4 m = red[j]; const float4 o = red[j+s];
            m.x += o.x; m.y += o.y; m.z += o.z; m.w += o.w;
            red[j] = m;
        }
        __syncthreads();
    }
    float4 var = red[0];
    var.x *= (1.0f/128.0f); var.y *= (1.0f/128.0f);
    var.z *= (1.0f/128.0f); var.w *= (1.0f/128.0f);

    const float gg = G[j], bb = Be[j];
    const float o0 = d0*rsqrtf(var.x+LN_EPS)*gg + bb;
    const float o1 = d1*rsqrtf(var.y+LN_EPS)*gg + bb;
    const float o2 = d2*rsqrtf(var.z+LN_EPS)*gg + bb;
    const float o3 = d3*rsqrtf(var.w+LN_EPS)*gg + bb;

    if (isq) {
        const float sc = 0.08838834764831845f;   // 1/sqrt(128)
        const int q0 = blk*4;
        qs[(size_t)(q0+0)*128 + j] = o0*sc;
        qs[(size_t)(q0+1)*128 + j] = o1*sc;
        qs[(size_t)(q0+2)*128 + j] = o2*sc;
        qs[(size_t)(q0+3)*128 + j] = o3*sc;
    } else {
        kmat[(size_t)(kidx0+0)*128 + j] = o0;
        kmat[(size_t)(kidx0+1)*128 + j] = o1;
        kmat[(size_t)(kidx0+2)*128 + j] = o2;
        kmat[(size_t)(kidx0+3)*128 + j] = o3;
    }
}

// ---------------------------------------------------------------------------
// Kernel 2: 512 blocks x 256 threads; each block = (b, 2 consecutive qi).
// Two 128-thread groups share kmat/mask/input via L1 (halves L2 traffic).
// e^{score} channel-independent; channels 32..63 analytic (att = 1 or 0);
// no max subtraction (|score| small, fp32 exp safe); branchless scan.
// ---------------------------------------------------------------------------
__global__ void k_attn(
    const float* __restrict__ input, const float* __restrict__ mask,
    const float* __restrict__ qs, const float* __restrict__ kmat,
    const float* __restrict__ attn_g, const float* __restrict__ attn_b,
    const float* __restrict__ out_w, const float* __restrict__ out_b,
    const float* __restrict__ out_g, const float* __restrict__ out_be,
    float* __restrict__ outm)
{
    const int blk = blockIdx.x;       // b*64 + qpair
    const int b   = blk >> 6;
    const int qp  = blk & 63;
    const int tid = threadIdx.x;      // 0..255
    const int grp = tid >> 7;         // 0/1 -> which qi
    const int tl  = tid & 127;
    const int qi  = qp*2 + grp;

    __shared__ __align__(16) float et[2][512];
    __shared__ __align__(16) float qsh[2][128];
    __shared__ __align__(16) float redA[2][128];
    __shared__ __align__(16) float redB[2][128];
    __shared__ __align__(16) float x2[2][64];

    qsh[grp][tl] = qs[(size_t)qi*128 + tl];
    __syncthreads();

    const float4* q4 = (const float4*)qsh[grp];
    #pragma unroll
    for (int it = 0; it < 4; ++it) {
        const int t = tl + it*128;
        const float4* kr = (const float4*)(kmat + (size_t)(b*512 + t)*128);
        float a0=0.f, a1=0.f, a2=0.f, a3=0.f;
        #pragma unroll
        for (int d4 = 0; d4 < 32; d4 += 4) {
            a0 += dot4(q4[d4+0], kr[d4+0]);
            a1 += dot4(q4[d4+1], kr[d4+1]);
            a2 += dot4(q4[d4+2], kr[d4+2]);
            a3 += dot4(q4[d4+3], kr[d4+3]);
        }
        et[grp][t] = __expf((a0+a1)+(a2+a3));
    }
    __syncthreads();

    // scan 32 input channels; 4 threads/channel, 128 keys each (branchless)
    const int c   = tl & 31;
    const int seg = tl >> 5;
    const float4* m4 = (const float4*)(mask  + (size_t)(b*32 + c)*512) + seg*32;
    const float4* x4 = (const float4*)(input + (size_t)(b*32 + c)*512) + seg*32;
    const float4* e4 = (const float4*)et[grp] + seg*32;

    float s = 0.f, a = 0.f;
    #pragma unroll 8
    for (int i = 0; i < 32; ++i) {
        const float4 mm = m4[i];
        const float4 xx = x4[i];
        const float4 ee = e4[i];
        const float wx = ee.x*(1.f-mm.x), wy = ee.y*(1.f-mm.y);
        const float wz = ee.z*(1.f-mm.z), ww = ee.w*(1.f-mm.w);
        s += (wx+wy)+(wz+ww);
        a += (wx*xx.x + wy*xx.y) + (wz*xx.z + ww*xx.w);
    }
    redA[grp][tl] = s; redB[grp][tl] = a;
    __syncthreads();

    float attv = 0.f;
    if (tl < 64) {
        if (tl < 32) {
            const float ss = redA[grp][tl]+redA[grp][tl+32]+redA[grp][tl+64]+redA[grp][tl+96];
            const float aa = redB[grp][tl]+redB[grp][tl+32]+redB[grp][tl+64]+redB[grp][tl+96];
            attv = (ss > 0.f) ? aa/ss : 0.f;
        } else {
            const int cc = tl - 32;
            const float ss = redA[grp][cc]+redA[grp][cc+32]+redA[grp][cc+64]+redA[grp][cc+96];
            attv = (ss > 0.f) ? 1.0f : 0.0f;
        }
    }
    __syncthreads();

    // LayerNorm over 64 channels
    redA[grp][tl] = (tl < 64) ? attv : 0.f;
    __syncthreads();
    for (int s2 = 64; s2 > 0; s2 >>= 1) {
        if (tl < s2) redA[grp][tl] += redA[grp][tl+s2];
        __syncthreads();
    }
    const float mean64 = redA[grp][0] * (1.0f/64.0f);
    __syncthreads();
    const float dv = attv - mean64;
    redA[grp][tl] = (tl < 64) ? dv*dv : 0.f;
    __syncthreads();
    for (int s2 = 64; s2 > 0; s2 >>= 1) {
        if (tl < s2) redA[grp][tl] += redA[grp][tl+s2];
        __syncthreads();
    }
    const float var64 = redA[grp][0] * (1.0f/64.0f);
    __syncthreads();
    if (tl < 64) x2[grp][tl] = dv*rsqrtf(var64+LN_EPS)*attn_g[tl] + attn_b[tl];
    __syncthreads();

    // out linear (128 x 64) + LayerNorm over 128
    float acc = out_b[tl];
    const float4* wr  = (const float4*)(out_w + (size_t)tl*64);
    const float4* x24 = (const float4*)x2[grp];
    #pragma unroll
    for (int d4 = 0; d4 < 16; ++d4) acc += dot4(wr[d4], x24[d4]);

    redA[grp][tl] = acc;
    __syncthreads();
    for (int s2 = 64; s2 > 0; s2 >>= 1) {
        if (tl < s2) redA[grp][tl] += redA[grp][tl+s2];
        __syncthreads();
    }
    const float mean128 = redA[grp][0] * (1.0f/128.0f);
    __syncthreads();
    const float d = acc - mean128;
    redA[grp][tl] = d*d;
    __syncthreads();
    for (int s2 = 64; s2 > 0; s2 >>= 1) {
        if (tl < s2) redA[grp][tl] += redA[grp][tl+s2];
        __syncthreads();
    }
    const float var128 = redA[grp][0] * (1.0f/128.0f);

    outm[(size_t)(b*128+qi)*128 + tl] =
        d*rsqrtf(var128+LN_EPS)*out_g[tl] + out_be[tl];
}

// ---------------------------------------------------------------------------
// Kernel 3: gi[qi][b][g] = outm[b,qi,:]·wih[g,:] + bih[g]
// ---------------------------------------------------------------------------
__global__ void k_gi(const float* __restrict__ outm,
                     const float* __restrict__ wih, const float* __restrict__ bih,
                     float* __restrict__ gi)
{
    const int qi  = blockIdx.x;
    const int tid = threadIdx.x;   // 0..383
    __shared__ __align__(16) float rows[8][128];
    for (int idx = tid; idx < 1024; idx += 384) {
        const int b = idx >> 7, d = idx & 127;
        rows[b][d] = outm[(size_t)(b*128+qi)*128 + d];
    }
    __syncthreads();

    const float4* wr = (const float4*)(wih + (size_t)tid*128);
    float acc[8] = {0,0,0,0,0,0,0,0};
    #pragma unroll 8
    for (int d4 = 0; d4 < 32; ++d4) {
        const float4 w4 = wr[d4];
        #pragma unroll
        for (int b = 0; b < 8; ++b)
            acc[b] += dot4(w4, ((const float4*)rows[b])[d4]);
    }
    const float bi = bih[tid];
    #pragma unroll
    for (int b = 0; b < 8; ++b)
        gi[((size_t)qi*8 + b)*384 + tid] = acc[b] + bi;
}

// ---------------------------------------------------------------------------
// Kernel 4: GRU recurrence + fused classifier. One block per batch row.
// 768 threads: each holds a 64-float slice of one whh row in 16 float4
// (64 VGPRs -> stays register-resident; R2's 128-VGPR version was demoted,
// VGPR_Count=84 proved it). Partials combined by gate threads via LDS.
// ---------------------------------------------------------------------------
__global__ void __launch_bounds__(768, 3) k_gru_cls(
    const float* __restrict__ gi,
    const float* __restrict__ whh, const float* __restrict__ bhh,
    const float* __restrict__ c1w, const float* __restrict__ c1b,
    const float* __restrict__ c2w, const float* __restrict__ c2b,
    const float* __restrict__ c3w, const float* __restrict__ c3b,
    float* __restrict__ out)
{
    const int b   = blockIdx.x;
    const int tid = threadIdx.x;                 // 0..767
    const int half = (tid >= 384) ? 1 : 0;
    const int g    = tid - half*384;             // 0..383

    __shared__ __align__(16) float h[2][128];
    __shared__ __align__(16) float part[2][384];

    // 64-float weight slice -> 16 float4 registers (loaded ONCE)
    float4 w[16];
    {
        const float4* wr = (const float4*)(whh + (size_t)g*128 + half*64);
        #pragma unroll
        for (int i = 0; i < 16; ++i) w[i] = wr[i];
    }

    const float* gbase = gi + (size_t)b*384;     // + qi*3072 per step
    float bh_r=0.f, bh_z=0.f, bh_n=0.f, gr0=0.f, gz0=0.f, gn0=0.f;
    if (tid < 128) {
        bh_r = bhh[tid]; bh_z = bhh[tid+128]; bh_n = bhh[tid+256];
        gr0 = gbase[tid]; gz0 = gbase[tid+128]; gn0 = gbase[tid+256];
        h[0][tid] = 0.f;
    }
    __syncthreads();

    int p = 0;
    for (int qi = 0; qi < 128; ++qi) {
        const float4* h4 = (const float4*)(&h[p][half*64]);
        float a0=0.f, a1=0.f, a2=0.f, a3=0.f;
        #pragma unroll
        for (int d4 = 0; d4 < 16; d4 += 4) {
            a0 += dot4(w[d4+0], h4[d4+0]);
            a1 += dot4(w[d4+1], h4[d4+1]);
            a2 += dot4(w[d4+2], h4[d4+2]);
            a3 += dot4(w[d4+3], h4[d4+3]);
        }
        part[half][g] = (a0+a1)+(a2+a3);

        // prefetch next step's gia while partials drain
        float grn=0.f, gzn=0.f, gnn=0.f;
        if (tid < 128 && qi < 127) {
            const float* gb = gbase + (size_t)(qi+1)*3072;
            grn = gb[tid]; gzn = gb[tid+128]; gnn = gb[tid+256];
        }
        __syncthreads();

        if (tid < 128) {
            const float ghr = part[0][tid]     + part[1][tid]     + bh_r;
            const float ghz = part[0][tid+128] + part[1][tid+128] + bh_z;
            const float ghn = part[0][tid+256] + part[1][tid+256] + bh_n;
            const float r = fast_sigmoid(gr0 + ghr);
            const float z = fast_sigmoid(gz0 + ghz);
            const float n = fast_tanh(gn0 + r*ghn);
            h[1-p][tid] = (1.f - z)*n + z*h[p][tid];
            gr0 = grn; gz0 = gzn; gn0 = gnn;
        }
        __syncthreads();
        p ^= 1;
    }

    // ---- fused classifier MLP (threads 0..127) ----
    float* pf = &part[0][0];   // 768-float scratch
    if (tid < 128) {
        float acc = c1b[tid];
        const float4* wc = (const float4*)(c1w + (size_t)tid*128);
        const float4* v  = (const float4*)h[p];
        #pragma unroll
        for (int d4 = 0; d4 < 32; ++d4) acc += dot4(wc[d4], v[d4]);
        pf[tid] = fmaxf(acc, 0.f);
    }
    __syncthreads();
    if (tid < 128) {
        float acc = c2b[tid];
        const float4* wc = (const float4*)(c2w + (size_t)tid*128);
        const float4* v  = (const float4*)pf;
        #pragma unroll
        for (int d4 = 0; d4 < 32; ++d4) acc += dot4(wc[d4], v[d4]);
        pf[384 + tid] = fmaxf(acc, 0.f);
    }
    __syncthreads();
    if (tid < 2) {
        float acc = c3b[tid];
        const float4* wc = (const float4*)(c3w + (size_t)tid*128);
        const float4* v  = (const float4*)(pf + 384);
        #pragma unroll
        for (int d4 = 0; d4 < 32; ++d4) acc += dot4(wc[d4], v[d4]);
        out[(size_t)b*2 + tid] = acc;
    }
}

// ---------------------------------------------------------------------------
extern "C" void kernel_launch(void* const* d_in, const int* in_sizes, int n_in,
                              void* d_out, int out_size, void* d_ws, size_t ws_size,
                              hipStream_t stream)
{
    const float* input     = (const float*)d_in[0];
    const float* mask      = (const float*)d_in[1];
    const float* timesteps = (const float*)d_in[2];
    const float* pw        = (const float*)d_in[3];
    const float* pb        = (const float*)d_in[4];
    const float* lw        = (const float*)d_in[5];
    const float* lb        = (const float*)d_in[6];
    const float* q_w       = (const float*)d_in[7];
    const float* q_b       = (const float*)d_in[8];
    const float* q_g       = (const float*)d_in[9];
    const float* q_be      = (const float*)d_in[10];
    const float* k_w       = (const float*)d_in[11];
    const float* k_b       = (const float*)d_in[12];
    const float* k_g       = (const float*)d_in[13];
    const float* k_be      = (const float*)d_in[14];
    const float* attn_g    = (const float*)d_in[15];
    const float* attn_b    = (const float*)d_in[16];
    const float* out_w     = (const float*)d_in[17];
    const float* out_b     = (const float*)d_in[18];
    const float* out_g     = (const float*)d_in[19];
    const float* out_be    = (const float*)d_in[20];
    const float* gru_wih   = (const float*)d_in[21];
    const float* gru_whh   = (const float*)d_in[22];
    const float* gru_bih   = (const float*)d_in[23];
    const float* gru_bhh   = (const float*)d_in[24];
    const float* c1_w      = (const float*)d_in[25];
    const float* c1_b      = (const float*)d_in[26];
    const float* c2_w      = (const float*)d_in[27];
    const float* c2_b      = (const float*)d_in[28];
    const float* c3_w      = (const float*)d_in[29];
    const float* c3_b      = (const float*)d_in[30];

    float* ws   = (float*)d_ws;
    float* qs   = ws;                    // 128*128        = 16384
    float* kmat = qs   + 16384;          // 8*512*128      = 524288
    float* outm = kmat + 524288;         // 8*128*128      = 131072
    float* gi   = outm + 131072;         // 128*8*384      = 393216

    k_embed_proj<<<1056, 128, 0, stream>>>(timesteps, pw, pb, lw, lb,
                                           q_w, q_b, q_g, q_be,
                                           k_w, k_b, k_g, k_be, qs, kmat);
    k_attn<<<512, 256, 0, stream>>>(input, mask, qs, kmat,
                                    attn_g, attn_b, out_w, out_b,
                                    out_g, out_be, outm);
    k_gi<<<128, 384, 0, stream>>>(outm, gru_wih, gru_bih, gi);
    k_gru_cls<<<8, 768, 0, stream>>>(gi, gru_whh, gru_bhh,
                                     c1_w, c1_b, c2_w, c2_b, c3_w, c3_b,
                                     (float*)d_out);
}

// Round 4
// 341.946 us; speedup vs baseline: 2.2767x; 1.0131x over previous
//
#include <hip/hip_runtime.h>
#include <math.h>

#define LN_EPS 1e-5f

__device__ __forceinline__ float dot4(float4 a, float4 b) {
    return a.x*b.x + a.y*b.y + a.z*b.z + a.w*b.w;
}
__device__ __forceinline__ float fast_sigmoid(float x) {
    return 1.f / (1.f + __expf(-x));
}
__device__ __forceinline__ float fast_tanh(float x) {
    const float e = __expf(2.f * x);
    return 1.f - 2.f / (e + 1.f);
}

// ---------------------------------------------------------------------------
// Kernel 1: time embedding + {q,k} projection + layer norm.
// Blocks 0..31   -> query rows (4/block, NT=128); 32..1055 -> key rows.
// q pre-scaled by 1/sqrt(128).
// ---------------------------------------------------------------------------
__global__ void k_embed_proj(
    const float* __restrict__ timesteps,
    const float* __restrict__ pw, const float* __restrict__ pb,
    const float* __restrict__ lw, const float* __restrict__ lb,
    const float* __restrict__ q_w, const float* __restrict__ q_b,
    const float* __restrict__ q_g, const float* __restrict__ q_be,
    const float* __restrict__ k_w, const float* __restrict__ k_b,
    const float* __restrict__ k_g, const float* __restrict__ k_be,
    float* __restrict__ qs, float* __restrict__ kmat)
{
    const int blk = blockIdx.x;
    const bool isq = blk < 32;
    const int j = threadIdx.x;            // 0..127

    __shared__ __align__(16) float e[4][128];
    __shared__ __align__(16) float4 red[128];

    float tv[4];
    int kidx0 = 0;
    if (isq) {
        const int q0 = blk * 4;
        #pragma unroll
        for (int r = 0; r < 4; ++r) tv[r] = (float)(q0 + r) * (1.0f/127.0f);
    } else {
        kidx0 = (blk - 32) * 4;
        #pragma unroll
        for (int r = 0; r < 4; ++r) tv[r] = timesteps[kidx0 + r];
    }

    float pwj = 0.f, pbj = 0.f;
    if (j > 0) { pwj = pw[j-1]; pbj = pb[j-1]; }
    const float lw0 = lw[0], lb0 = lb[0];
    #pragma unroll
    for (int r = 0; r < 4; ++r)
        e[r][j] = (j == 0) ? (tv[r]*lw0 + lb0) : sinf(tv[r]*pwj + pbj);
    __syncthreads();

    const float* W  = isq ? q_w  : k_w;
    const float* Bv = isq ? q_b  : k_b;
    const float* G  = isq ? q_g  : k_g;
    const float* Be = isq ? q_be : k_be;

    float acc[4];
    const float bj = Bv[j];
    #pragma unroll
    for (int r = 0; r < 4; ++r) acc[r] = bj;

    const float4* wr = (const float4*)(W + (size_t)j*128);
    const float4* e0 = (const float4*)(&e[0][0]);
    const float4* e1 = (const float4*)(&e[1][0]);
    const float4* e2 = (const float4*)(&e[2][0]);
    const float4* e3 = (const float4*)(&e[3][0]);
    #pragma unroll
    for (int d4 = 0; d4 < 32; ++d4) {
        const float4 w4 = wr[d4];
        acc[0] += dot4(w4, e0[d4]);
        acc[1] += dot4(w4, e1[d4]);
        acc[2] += dot4(w4, e2[d4]);
        acc[3] += dot4(w4, e3[d4]);
    }

    red[j] = make_float4(acc[0], acc[1], acc[2], acc[3]);
    __syncthreads();
    for (int s = 64; s > 0; s >>= 1) {
        if (j < s) {
            float4 m = red[j]; const float4 o = red[j+s];
            m.x += o.x; m.y += o.y; m.z += o.z; m.w += o.w;
            red[j] = m;
        }
        __syncthreads();
    }
    float4 mean = red[0];
    mean.x *= (1.0f/128.0f); mean.y *= (1.0f/128.0f);
    mean.z *= (1.0f/128.0f); mean.w *= (1.0f/128.0f);
    __syncthreads();
    const float d0 = acc[0]-mean.x, d1 = acc[1]-mean.y,
                d2 = acc[2]-mean.z, d3 = acc[3]-mean.w;
    red[j] = make_float4(d0*d0, d1*d1, d2*d2, d3*d3);
    __syncthreads();
    for (int s = 64; s > 0; s >>= 1) {
        if (j < s) {
            float4 m = red[j]; const float4 o = red[j+s];
            m.x += o.x; m.y += o.y; m.z += o.z; m.w += o.w;
            red[j] = m;
        }
        __syncthreads();
    }
    float4 var = red[0];
    var.x *= (1.0f/128.0f); var.y *= (1.0f/128.0f);
    var.z *= (1.0f/128.0f); var.w *= (1.0f/128.0f);

    const float gg = G[j], bb = Be[j];
    const float o0 = d0*rsqrtf(var.x+LN_EPS)*gg + bb;
    const float o1 = d1*rsqrtf(var.y+LN_EPS)*gg + bb;
    const float o2 = d2*rsqrtf(var.z+LN_EPS)*gg + bb;
    const float o3 = d3*rsqrtf(var.w+LN_EPS)*gg + bb;

    if (isq) {
        const float sc = 0.08838834764831845f;   // 1/sqrt(128)
        const int q0 = blk*4;
        qs[(size_t)(q0+0)*128 + j] = o0*sc;
        qs[(size_t)(q0+1)*128 + j] = o1*sc;
        qs[(size_t)(q0+2)*128 + j] = o2*sc;
        qs[(size_t)(q0+3)*128 + j] = o3*sc;
    } else {
        kmat[(size_t)(kidx0+0)*128 + j] = o0;
        kmat[(size_t)(kidx0+1)*128 + j] = o1;
        kmat[(size_t)(kidx0+2)*128 + j] = o2;
        kmat[(size_t)(kidx0+3)*128 + j] = o3;
    }
}

// ---------------------------------------------------------------------------
// Kernel 2: 512 blocks x 256 threads; each block = (b, 2 consecutive qi).
// e^{score} channel-independent; channels 32..63 analytic; branchless scan.
// ---------------------------------------------------------------------------
__global__ void k_attn(
    const float* __restrict__ input, const float* __restrict__ mask,
    const float* __restrict__ qs, const float* __restrict__ kmat,
    const float* __restrict__ attn_g, const float* __restrict__ attn_b,
    const float* __restrict__ out_w, const float* __restrict__ out_b,
    const float* __restrict__ out_g, const float* __restrict__ out_be,
    float* __restrict__ outm)
{
    const int blk = blockIdx.x;       // b*64 + qpair
    const int b   = blk >> 6;
    const int qp  = blk & 63;
    const int tid = threadIdx.x;      // 0..255
    const int grp = tid >> 7;         // 0/1 -> which qi
    const int tl  = tid & 127;
    const int qi  = qp*2 + grp;

    __shared__ __align__(16) float et[2][512];
    __shared__ __align__(16) float qsh[2][128];
    __shared__ __align__(16) float redA[2][128];
    __shared__ __align__(16) float redB[2][128];
    __shared__ __align__(16) float x2[2][64];

    qsh[grp][tl] = qs[(size_t)qi*128 + tl];
    __syncthreads();

    const float4* q4 = (const float4*)qsh[grp];
    #pragma unroll
    for (int it = 0; it < 4; ++it) {
        const int t = tl + it*128;
        const float4* kr = (const float4*)(kmat + (size_t)(b*512 + t)*128);
        float a0=0.f, a1=0.f, a2=0.f, a3=0.f;
        #pragma unroll
        for (int d4 = 0; d4 < 32; d4 += 4) {
            a0 += dot4(q4[d4+0], kr[d4+0]);
            a1 += dot4(q4[d4+1], kr[d4+1]);
            a2 += dot4(q4[d4+2], kr[d4+2]);
            a3 += dot4(q4[d4+3], kr[d4+3]);
        }
        et[grp][t] = __expf((a0+a1)+(a2+a3));
    }
    __syncthreads();

    const int c   = tl & 31;
    const int seg = tl >> 5;
    const float4* m4 = (const float4*)(mask  + (size_t)(b*32 + c)*512) + seg*32;
    const float4* x4 = (const float4*)(input + (size_t)(b*32 + c)*512) + seg*32;
    const float4* e4 = (const float4*)et[grp] + seg*32;

    float s = 0.f, a = 0.f;
    #pragma unroll 8
    for (int i = 0; i < 32; ++i) {
        const float4 mm = m4[i];
        const float4 xx = x4[i];
        const float4 ee = e4[i];
        const float wx = ee.x*(1.f-mm.x), wy = ee.y*(1.f-mm.y);
        const float wz = ee.z*(1.f-mm.z), ww = ee.w*(1.f-mm.w);
        s += (wx+wy)+(wz+ww);
        a += (wx*xx.x + wy*xx.y) + (wz*xx.z + ww*xx.w);
    }
    redA[grp][tl] = s; redB[grp][tl] = a;
    __syncthreads();

    float attv = 0.f;
    if (tl < 64) {
        if (tl < 32) {
            const float ss = redA[grp][tl]+redA[grp][tl+32]+redA[grp][tl+64]+redA[grp][tl+96];
            const float aa = redB[grp][tl]+redB[grp][tl+32]+redB[grp][tl+64]+redB[grp][tl+96];
            attv = (ss > 0.f) ? aa/ss : 0.f;
        } else {
            const int cc = tl - 32;
            const float ss = redA[grp][cc]+redA[grp][cc+32]+redA[grp][cc+64]+redA[grp][cc+96];
            attv = (ss > 0.f) ? 1.0f : 0.0f;
        }
    }
    __syncthreads();

    redA[grp][tl] = (tl < 64) ? attv : 0.f;
    __syncthreads();
    for (int s2 = 64; s2 > 0; s2 >>= 1) {
        if (tl < s2) redA[grp][tl] += redA[grp][tl+s2];
        __syncthreads();
    }
    const float mean64 = redA[grp][0] * (1.0f/64.0f);
    __syncthreads();
    const float dv = attv - mean64;
    redA[grp][tl] = (tl < 64) ? dv*dv : 0.f;
    __syncthreads();
    for (int s2 = 64; s2 > 0; s2 >>= 1) {
        if (tl < s2) redA[grp][tl] += redA[grp][tl+s2];
        __syncthreads();
    }
    const float var64 = redA[grp][0] * (1.0f/64.0f);
    __syncthreads();
    if (tl < 64) x2[grp][tl] = dv*rsqrtf(var64+LN_EPS)*attn_g[tl] + attn_b[tl];
    __syncthreads();

    float acc = out_b[tl];
    const float4* wr  = (const float4*)(out_w + (size_t)tl*64);
    const float4* x24 = (const float4*)x2[grp];
    #pragma unroll
    for (int d4 = 0; d4 < 16; ++d4) acc += dot4(wr[d4], x24[d4]);

    redA[grp][tl] = acc;
    __syncthreads();
    for (int s2 = 64; s2 > 0; s2 >>= 1) {
        if (tl < s2) redA[grp][tl] += redA[grp][tl+s2];
        __syncthreads();
    }
    const float mean128 = redA[grp][0] * (1.0f/128.0f);
    __syncthreads();
    const float d = acc - mean128;
    redA[grp][tl] = d*d;
    __syncthreads();
    for (int s2 = 64; s2 > 0; s2 >>= 1) {
        if (tl < s2) redA[grp][tl] += redA[grp][tl+s2];
        __syncthreads();
    }
    const float var128 = redA[grp][0] * (1.0f/128.0f);

    outm[(size_t)(b*128+qi)*128 + tl] =
        d*rsqrtf(var128+LN_EPS)*out_g[tl] + out_be[tl];
}

// ---------------------------------------------------------------------------
// Kernel 3: gi[qi][b][g] = outm[b,qi,:]·wih[g,:] + bih[g]
// ---------------------------------------------------------------------------
__global__ void k_gi(const float* __restrict__ outm,
                     const float* __restrict__ wih, const float* __restrict__ bih,
                     float* __restrict__ gi)
{
    const int qi  = blockIdx.x;
    const int tid = threadIdx.x;   // 0..383
    __shared__ __align__(16) float rows[8][128];
    for (int idx = tid; idx < 1024; idx += 384) {
        const int b = idx >> 7, d = idx & 127;
        rows[b][d] = outm[(size_t)(b*128+qi)*128 + d];
    }
    __syncthreads();

    const float4* wr = (const float4*)(wih + (size_t)tid*128);
    float acc[8] = {0,0,0,0,0,0,0,0};
    #pragma unroll 8
    for (int d4 = 0; d4 < 32; ++d4) {
        const float4 w4 = wr[d4];
        #pragma unroll
        for (int b = 0; b < 8; ++b)
            acc[b] += dot4(w4, ((const float4*)rows[b])[d4]);
    }
    const float bi = bih[tid];
    #pragma unroll
    for (int b = 0; b < 8; ++b)
        gi[((size_t)qi*8 + b)*384 + tid] = acc[b] + bi;
}

// ---------------------------------------------------------------------------
// Kernel 4: GRU + fused classifier. One block per batch row, 256 threads.
// Thread (s,u): s=tid>>7 (k-half), u=tid&127 (hidden unit). Each thread
// computes ALL THREE gate rows (u, u+128, u+256) over its 64-float k-slice:
// each h float4 LDS read feeds 3 accumulators -> LDS broadcast traffic
// drops 196KB -> 64KB per step (R3 was LDS-pipe bound at ~2690 cyc/step).
// s==0 keeps its partials in registers and reads only s==1's 3 floats.
// ---------------------------------------------------------------------------
__global__ void __launch_bounds__(256, 1) k_gru_cls(
    const float* __restrict__ gi,
    const float* __restrict__ whh, const float* __restrict__ bhh,
    const float* __restrict__ c1w, const float* __restrict__ c1b,
    const float* __restrict__ c2w, const float* __restrict__ c2b,
    const float* __restrict__ c3w, const float* __restrict__ c3b,
    float* __restrict__ out)
{
    const int b   = blockIdx.x;
    const int tid = threadIdx.x;                 // 0..255
    const int s   = tid >> 7;                    // k-half
    const int u   = tid & 127;                   // hidden unit

    __shared__ __align__(16) float h[2][128];
    __shared__ __align__(16) float part3[3][128];

    // 3 gate-row slices (64 floats each) -> 48 float4 registers, loaded ONCE
    float4 wr[16], wz[16], wn[16];
    {
        const float4* pr = (const float4*)(whh + (size_t)u*128       + s*64);
        const float4* pz = (const float4*)(whh + (size_t)(u+128)*128 + s*64);
        const float4* pn = (const float4*)(whh + (size_t)(u+256)*128 + s*64);
        #pragma unroll
        for (int i = 0; i < 16; ++i) { wr[i] = pr[i]; wz[i] = pz[i]; wn[i] = pn[i]; }
    }

    const float* gbase = gi + (size_t)b*384;     // + qi*3072 per step
    float bh_r=0.f, bh_z=0.f, bh_n=0.f, gr0=0.f, gz0=0.f, gn0=0.f, hprev=0.f;
    if (s == 0) {
        bh_r = bhh[u]; bh_z = bhh[u+128]; bh_n = bhh[u+256];
        gr0 = gbase[u]; gz0 = gbase[u+128]; gn0 = gbase[u+256];
        h[0][u] = 0.f;
    }
    __syncthreads();

    int p = 0;
    for (int qi = 0; qi < 128; ++qi) {
        const float4* h4 = (const float4*)(&h[p][s*64]);
        float ar = 0.f, az = 0.f, an = 0.f;
        #pragma unroll
        for (int i = 0; i < 16; ++i) {
            const float4 hv = h4[i];
            ar += dot4(wr[i], hv);
            az += dot4(wz[i], hv);
            an += dot4(wn[i], hv);
        }
        if (s == 1) { part3[0][u] = ar; part3[1][u] = az; part3[2][u] = an; }

        // prefetch next step's gia while partials drain
        float grn=0.f, gzn=0.f, gnn=0.f;
        if (s == 0 && qi < 127) {
            const float* gb = gbase + (size_t)(qi+1)*3072;
            grn = gb[u]; gzn = gb[u+128]; gnn = gb[u+256];
        }
        __syncthreads();

        if (s == 0) {
            const float ghr = ar + part3[0][u] + bh_r;
            const float ghz = az + part3[1][u] + bh_z;
            const float ghn = an + part3[2][u] + bh_n;
            const float r = fast_sigmoid(gr0 + ghr);
            const float z = fast_sigmoid(gz0 + ghz);
            const float n = fast_tanh(gn0 + r*ghn);
            const float hn2 = (1.f - z)*n + z*hprev;
            h[1-p][u] = hn2;
            hprev = hn2;
            gr0 = grn; gz0 = gzn; gn0 = gnn;
        }
        __syncthreads();
        p ^= 1;
    }

    // ---- fused classifier MLP (threads 0..127; h[p] = last hidden) ----
    if (tid < 128) {
        float acc = c1b[u];
        const float4* wc = (const float4*)(c1w + (size_t)u*128);
        const float4* v  = (const float4*)h[p];
        #pragma unroll
        for (int d4 = 0; d4 < 32; ++d4) acc += dot4(wc[d4], v[d4]);
        part3[0][u] = fmaxf(acc, 0.f);
    }
    __syncthreads();
    if (tid < 128) {
        float acc = c2b[u];
        const float4* wc = (const float4*)(c2w + (size_t)u*128);
        const float4* v  = (const float4*)part3[0];
        #pragma unroll
        for (int d4 = 0; d4 < 32; ++d4) acc += dot4(wc[d4], v[d4]);
        part3[1][u] = fmaxf(acc, 0.f);
    }
    __syncthreads();
    if (tid < 2) {
        float acc = c3b[tid];
        const float4* wc = (const float4*)(c3w + (size_t)tid*128);
        const float4* v  = (const float4*)part3[1];
        #pragma unroll
        for (int d4 = 0; d4 < 32; ++d4) acc += dot4(wc[d4], v[d4]);
        out[(size_t)b*2 + tid] = acc;
    }
}

// ---------------------------------------------------------------------------
extern "C" void kernel_launch(void* const* d_in, const int* in_sizes, int n_in,
                              void* d_out, int out_size, void* d_ws, size_t ws_size,
                              hipStream_t stream)
{
    const float* input     = (const float*)d_in[0];
    const float* mask      = (const float*)d_in[1];
    const float* timesteps = (const float*)d_in[2];
    const float* pw        = (const float*)d_in[3];
    const float* pb        = (const float*)d_in[4];
    const float* lw        = (const float*)d_in[5];
    const float* lb        = (const float*)d_in[6];
    const float* q_w       = (const float*)d_in[7];
    const float* q_b       = (const float*)d_in[8];
    const float* q_g       = (const float*)d_in[9];
    const float* q_be      = (const float*)d_in[10];
    const float* k_w       = (const float*)d_in[11];
    const float* k_b       = (const float*)d_in[12];
    const float* k_g       = (const float*)d_in[13];
    const float* k_be      = (const float*)d_in[14];
    const float* attn_g    = (const float*)d_in[15];
    const float* attn_b    = (const float*)d_in[16];
    const float* out_w     = (const float*)d_in[17];
    const float* out_b     = (const float*)d_in[18];
    const float* out_g     = (const float*)d_in[19];
    const float* out_be    = (const float*)d_in[20];
    const float* gru_wih   = (const float*)d_in[21];
    const float* gru_whh   = (const float*)d_in[22];
    const float* gru_bih   = (const float*)d_in[23];
    const float* gru_bhh   = (const float*)d_in[24];
    const float* c1_w      = (const float*)d_in[25];
    const float* c1_b      = (const float*)d_in[26];
    const float* c2_w      = (const float*)d_in[27];
    const float* c2_b      = (const float*)d_in[28];
    const float* c3_w      = (const float*)d_in[29];
    const float* c3_b      = (const float*)d_in[30];

    float* ws   = (float*)d_ws;
    float* qs   = ws;                    // 128*128        = 16384
    float* kmat = qs   + 16384;          // 8*512*128      = 524288
    float* outm = kmat + 524288;         // 8*128*128      = 131072
    float* gi   = outm + 131072;         // 128*8*384      = 393216

    k_embed_proj<<<1056, 128, 0, stream>>>(timesteps, pw, pb, lw, lb,
                                           q_w, q_b, q_g, q_be,
                                           k_w, k_b, k_g, k_be, qs, kmat);
    k_attn<<<512, 256, 0, stream>>>(input, mask, qs, kmat,
                                    attn_g, attn_b, out_w, out_b,
                                    out_g, out_be, outm);
    k_gi<<<128, 384, 0, stream>>>(outm, gru_wih, gru_bih, gi);
    k_gru_cls<<<8, 256, 0, stream>>>(gi, gru_whh, gru_bhh,
                                     c1_w, c1_b, c2_w, c2_b, c3_w, c3_b,
                                     (float*)d_out);
}